// Round 1
// baseline (60.344 us; speedup 1.0000x reference)
//
#include <hip/hip_runtime.h>

// NeuralQuantizer: out[i] = nearest center to x[i], centers = linspace(-1,1,256).
// Closed form: idx = clamp(round((x+1)*127.5), 0, 255); q = -1 + idx*(2/255).
// Memory-bound elementwise op: float4 vectorized, one pass.

__device__ __forceinline__ float quant1(float v) {
    float t = (v + 1.0f) * 127.5f;
    // round-to-nearest-even, then clamp to [0,255]
    float idx = __builtin_rintf(t);
    idx = fminf(fmaxf(idx, 0.0f), 255.0f);
    return fmaf(idx, 2.0f / 255.0f, -1.0f);
}

__global__ __launch_bounds__(256) void quantize_f4(const float4* __restrict__ x,
                                                   float4* __restrict__ out,
                                                   int n4) {
    int i = blockIdx.x * blockDim.x + threadIdx.x;
    if (i < n4) {
        float4 v = x[i];
        float4 o;
        o.x = quant1(v.x);
        o.y = quant1(v.y);
        o.z = quant1(v.z);
        o.w = quant1(v.w);
        out[i] = o;
    }
}

extern "C" void kernel_launch(void* const* d_in, const int* in_sizes, int n_in,
                              void* d_out, int out_size, void* d_ws, size_t ws_size,
                              hipStream_t stream) {
    const float4* x = (const float4*)d_in[0];
    float4* out = (float4*)d_out;
    int n = in_sizes[0];            // 2,097,152 — divisible by 4
    int n4 = n / 4;
    int block = 256;
    int grid = (n4 + block - 1) / block;   // 2048 blocks
    quantize_f4<<<grid, block, 0, stream>>>(x, out, n4);
}